// Round 3
// baseline (396.277 us; speedup 1.0000x reference)
//
#include <hip/hip_runtime.h>
#include <hip/hip_bf16.h>
#include <math.h>
#include <stdint.h>

#define NNODES 50000
#define SCHUNK 4096
#define AW 1664          // total K: 3*512 agg + 128 x
#define XOFF 1536

typedef __bf16 bf16x8 __attribute__((ext_vector_type(8)));
typedef float f32x4 __attribute__((ext_vector_type(4)));
typedef unsigned short u16;
typedef unsigned int u32;

__device__ __forceinline__ float lrelu(float x){ return x >= 0.f ? x : 0.2f*x; }
__device__ __forceinline__ float lo2f(u32 v){ union{ u32 i; float f; } c; c.i = v<<16; return c.f; }
__device__ __forceinline__ float hi2f(u32 v){ union{ u32 i; float f; } c; c.i = v & 0xffff0000u; return c.f; }
__device__ __forceinline__ u16 f2b(float f){ __hip_bfloat16 h = __float2bfloat16(f); return *(u16*)&h; }
__device__ __forceinline__ u32 packbf(float a, float b){ return (u32)f2b(a) | ((u32)f2b(b) << 16); }

// global -> LDS direct DMA, 16B per lane, LDS dest = wave-uniform base + lane*16
#define GLDS16(g, l) __builtin_amdgcn_global_load_lds( \
    (const __attribute__((address_space(1))) void*)(g), \
    (__attribute__((address_space(3))) void*)(l), 16, 0, 0)

// ---- prep: stacked B per layer in K-CHUNK-MAJOR layout [K/8][128 cols][8 k] ----
// element (col c, k j) -> (j>>3)*1024 + c*8 + (j&7). Bias fold unchanged.
__global__ void prep_b(const float* __restrict__ W0, const float* __restrict__ W1,
                       const float* __restrict__ resW0, const float* __restrict__ resW1,
                       const float* __restrict__ b0, const float* __restrict__ b1,
                       u16* __restrict__ Btb, float* __restrict__ biasf)
{
    int gid = blockIdx.x*blockDim.x + threadIdx.x;
    if (gid < 2*128*AW){
        int l = gid / (128*AW);
        int rem = gid - l*(128*AW);
        int c = rem / AW;
        int j = rem - c*AW;
        const float* W  = l ? W1 : W0;
        const float* rw = l ? resW1 : resW0;
        float v;
        if (j < XOFF){
            int r = j >> 9, h = (j >> 7) & 3, k = j & 127;
            v = 0.25f * W[(size_t)r*65536 + (size_t)k*512 + h*128 + c];
        } else {
            int k = j - XOFF;
            float s = 0.f;
            for (int r = 0; r < 3; ++r)
                for (int h = 0; h < 4; ++h)
                    s += rw[(size_t)r*65536 + (size_t)k*512 + h*128 + c];
            v = 0.25f * s;
        }
        Btb[(size_t)l*128*AW + (size_t)(j>>3)*1024 + c*8 + (j&7)] = f2b(v);
    }
    if (gid < 256){
        int l = gid >> 7, c = gid & 127;
        const float* bb = l ? b1 : b0;
        float s = 0.f;
        for (int r = 0; r < 3; ++r)
            for (int h = 0; h < 4; ++h)
                s += bb[r*512 + h*128 + c];
        biasf[gid] = 0.25f*s;
    }
}

// ---- prep: wl (128 cols x 128 k) per layer, fcW transpose (unchanged layouts) ----
__global__ void prep_wl(const float* __restrict__ W0, const float* __restrict__ W1,
                        const float* __restrict__ al0, const float* __restrict__ ar0,
                        const float* __restrict__ al1, const float* __restrict__ ar1,
                        const float* __restrict__ fcW,
                        u16* __restrict__ wlb, u16* __restrict__ fcWtb)
{
    int gid = blockIdx.x*blockDim.x + threadIdx.x;
    if (gid < 2*128*128){
        int l = gid >> 14;
        int col = (gid >> 7) & 127;
        int k = gid & 127;
        float v = 0.f;
        if (col < 24){
            int r = col >> 3, lr = (col >> 2) & 1, h = col & 3;
            const float* W = l ? W1 : W0;
            const float* av = l ? (lr ? ar1 : al1) : (lr ? ar0 : al0);
            const float* wrow = W + (size_t)r*65536 + (size_t)k*512 + h*128;
            const float* arow = av + r*512 + h*128;
            for (int cc = 0; cc < 128; ++cc) v += wrow[cc]*arow[cc];
        }
        wlb[gid] = f2b(v);
    }
    if (gid < 128*128){
        int k = gid & 127, n = gid >> 7;
        fcWtb[gid] = f2b(fcW[k*128 + n]);
    }
}

// ---- xprep: x fp32 -> dense bf16 Xg (stride 128) + el0 = x @ wl0 via MFMA ----
__global__ __launch_bounds__(256) void xprep_kernel(const float* __restrict__ x,
    u16* __restrict__ Xg, const u16* __restrict__ wl, float* __restrict__ el, int M)
{
    __shared__ u16 Xs[64*136];
    __shared__ u16 Ws[32*136];
    const int tid = threadIdx.x;
    const int row0 = blockIdx.x*64;
    #pragma unroll
    for (int p = 0; p < 2; ++p){
        int idx = tid + p*256;
        int c = idx >> 4, kc = (idx & 15)*8;
        float4 v = make_float4(0.f,0.f,0.f,0.f);
        if (c < 24) v = *(const float4*)(wl + c*128 + kc);
        *(float4*)&Ws[c*136 + kc] = v;
    }
    int r = tid >> 2, cq = (tid & 3)*32;
    int grow = row0 + r;
    if (grow < M){
        #pragma unroll
        for (int i = 0; i < 8; ++i){
            float4 v = *(const float4*)(x + (size_t)grow*128 + cq + i*4);
            ushort4 o;
            o.x = f2b(v.x); o.y = f2b(v.y); o.z = f2b(v.z); o.w = f2b(v.w);
            *(ushort4*)(Xg + (size_t)grow*128 + cq + i*4) = o;
            *(ushort4*)&Xs[r*136 + cq + i*4] = o;
        }
    } else {
        ushort4 z; z.x=0; z.y=0; z.z=0; z.w=0;
        #pragma unroll
        for (int i = 0; i < 8; ++i) *(ushort4*)&Xs[r*136 + cq + i*4] = z;
    }
    __syncthreads();
    const int lane = tid & 63, wave = tid >> 6;
    const int r16 = lane & 15, quad = lane >> 4;
    f32x4 acc0 = {}, acc1 = {};
    #pragma unroll
    for (int ks = 0; ks < 4; ++ks){
        int ko = ks*32 + quad*8;
        bf16x8 a  = *(const bf16x8*)&Xs[(wave*16 + r16)*136 + ko];
        bf16x8 b0 = *(const bf16x8*)&Ws[r16*136 + ko];
        bf16x8 b1 = *(const bf16x8*)&Ws[(16 + r16)*136 + ko];
        acc0 = __builtin_amdgcn_mfma_f32_16x16x32_bf16(a, b0, acc0, 0,0,0);
        acc1 = __builtin_amdgcn_mfma_f32_16x16x32_bf16(a, b1, acc1, 0,0,0);
    }
    #pragma unroll
    for (int p = 0; p < 4; ++p){
        int row = row0 + wave*16 + quad*4 + p;
        if (row < M){
            el[(size_t)row*32 + r16] = acc0[p];
            if (r16 < 8) el[(size_t)row*32 + 16 + r16] = acc1[p];
        }
    }
}

// ---- CSR build (fused over relations) ----
__global__ void hist_all(const int* __restrict__ d0, const int* __restrict__ d1,
                         const int* __restrict__ d2, int e0, int e1, int e2,
                         int* __restrict__ cnt)
{
    int g = blockIdx.x*blockDim.x + threadIdx.x;
    if (g >= e0 + e1 + e2) return;
    int rel, idx;
    if (g < e0){ rel = 0; idx = g; }
    else if (g < e0 + e1){ rel = 1; idx = g - e0; }
    else { rel = 2; idx = g - e0 - e1; }
    const int* d = rel == 0 ? d0 : (rel == 1 ? d1 : d2);
    atomicAdd(cnt + (size_t)rel*NNODES + d[idx], 1);
}

__global__ __launch_bounds__(256) void scan_part(const int* __restrict__ cnt_all,
                                                 int* __restrict__ partials, int Nn, int nblk)
{
    int rel = blockIdx.y, blk = blockIdx.x;
    const int* cnt = cnt_all + (size_t)rel*Nn;
    int tid = threadIdx.x;
    int i0 = blk*SCHUNK + tid*16;
    int s = 0;
    #pragma unroll
    for (int k = 0; k < 4; ++k){
        int idx = i0 + k*4;
        if (idx + 3 < Nn){ int4 v = *(const int4*)(cnt + idx); s += v.x+v.y+v.z+v.w; }
        else { for (int j = 0; j < 4; ++j) if (idx+j < Nn) s += cnt[idx+j]; }
    }
    #pragma unroll
    for (int off = 1; off < 64; off <<= 1) s += __shfl_xor(s, off);
    __shared__ int ws[4];
    if ((tid & 63) == 0) ws[tid>>6] = s;
    __syncthreads();
    if (tid == 0) partials[rel*nblk + blk] = ws[0]+ws[1]+ws[2]+ws[3];
}

__global__ __launch_bounds__(256) void scan_write(const int* __restrict__ cnt_all,
                                                  const int* __restrict__ partials,
                                                  int* __restrict__ rp_all, int* __restrict__ cur_all,
                                                  int Nn, int nblk)
{
    int rel = blockIdx.y, blk = blockIdx.x;
    const int* cnt = cnt_all + (size_t)rel*Nn;
    int* rp  = rp_all  + (size_t)rel*(Nn+1);
    int* cur = cur_all + (size_t)rel*Nn;
    int tid = threadIdx.x;
    __shared__ int sOff;
    __shared__ int wsum[4];
    if (tid == 0){
        int o = 0;
        for (int b = 0; b < blk; ++b) o += partials[rel*nblk + b];
        sOff = o;
        if (blk == 0){
            int t = 0;
            for (int b = 0; b < nblk; ++b) t += partials[rel*nblk + b];
            rp[Nn] = t;
        }
    }
    int i0 = blk*SCHUNK + tid*16;
    int v[16];
    int s = 0;
    #pragma unroll
    for (int k = 0; k < 16; ++k){
        int idx = i0 + k;
        v[k] = (idx < Nn) ? cnt[idx] : 0;
        s += v[k];
    }
    int lane = tid & 63;
    int incl = s;
    #pragma unroll
    for (int off = 1; off < 64; off <<= 1){
        int t = __shfl_up(incl, off);
        if (lane >= off) incl += t;
    }
    if (lane == 63) wsum[tid>>6] = incl;
    __syncthreads();
    int woff = 0;
    for (int w = 0; w < (tid>>6); ++w) woff += wsum[w];
    int ex = sOff + woff + incl - s;
    #pragma unroll
    for (int k = 0; k < 16; ++k){
        int idx = i0 + k;
        if (idx < Nn){ rp[idx] = ex; cur[idx] = ex; }
        ex += v[k];
    }
}

__global__ void scatter_all(const int* __restrict__ s0, const int* __restrict__ s1,
                            const int* __restrict__ s2,
                            const int* __restrict__ d0, const int* __restrict__ d1,
                            const int* __restrict__ d2, int e0, int e1, int e2,
                            int* __restrict__ cur, int* __restrict__ colb,
                            int* __restrict__ dste)
{
    int g = blockIdx.x*blockDim.x + threadIdx.x;
    if (g >= e0 + e1 + e2) return;
    int rel, idx, coff;
    if (g < e0){ rel = 0; idx = g; coff = 0; }
    else if (g < e0 + e1){ rel = 1; idx = g - e0; coff = e0; }
    else { rel = 2; idx = g - e0 - e1; coff = e0 + e1; }
    const int* sp = rel == 0 ? s0 : (rel == 1 ? s1 : s2);
    const int* dp = rel == 0 ? d0 : (rel == 1 ? d1 : d2);
    int d = dp[idx];
    int pos = atomicAdd(cur + (size_t)rel*NNODES + d, 1);
    colb[coff + pos] = sp[idx];
    dste[coff + pos] = d;
}

// ---- edge-parallel unnormalized weights -> packed 16B edge records ----
__global__ void wprep(const int* __restrict__ colb, const int* __restrict__ dste,
                      int e0, int e01, int etot,
                      const float* __restrict__ el_all, uint4* __restrict__ rec)
{
    int j = blockIdx.x*blockDim.x + threadIdx.x;
    if (j >= etot) return;
    int rel = (j < e0) ? 0 : ((j < e01) ? 1 : 2);
    int src = colb[j], dst = dste[j];
    float4 es = *(const float4*)(el_all + (size_t)src*32 + rel*8);
    float4 ed = *(const float4*)(el_all + (size_t)dst*32 + rel*8 + 4);
    uint4 o;
    o.x = (u32)src;
    o.y = packbf(__expf(lrelu(es.x + ed.x)), __expf(lrelu(es.y + ed.y)));
    o.z = packbf(__expf(lrelu(es.z + ed.z)), __expf(lrelu(es.w + ed.w)));
    o.w = 0;
    rec[j] = o;
}

// ---- FUSED aggregation + GEMM ----
// Block: 64 nodes, 256 threads. Wave w owns 16 rows (nodes), all 128 cols.
// Aggregation happens IN REGISTERS in MFMA A-fragment layout: lane(r16=node,
// quad) accumulates k-cols {h*128 + m*32 + quad*8 ..+7} in fp32 (ac[4][4][8]),
// normalizes, packs to 16 bf16x8 frags -> 16 MFMA k-steps per rel.
// B is staged per 32-k step (8KB) via global_load_lds from k-chunk-major Btg:
// stage source is LINEAR (perfectly coalesced), LDS layout [quad][col][16B]
// is bank-even for the frag reads. x-part (k 1536..1663) reads Xg directly.
template<int EPI>
__global__ __launch_bounds__(256, 2) void fused_gat(
    const int* __restrict__ rowp_all, const uint4* __restrict__ rec_all,
    int e0, int e01,
    const u16* __restrict__ Xg, const u16* __restrict__ Btg,
    float* __restrict__ Cf, u16* __restrict__ Cb, int M,
    const float* __restrict__ bias)
{
    __shared__ u16 smem[8192];   // 2 x 8KB B double-buffer
    const int tid = threadIdx.x;
    const int lane = tid & 63, wave = tid >> 6;
    const int r16 = lane & 15, quad = lane >> 4;
    const int row0 = blockIdx.x*64;
    const int nd = row0 + wave*16 + r16;

    f32x4 cacc[8] = {};
    bf16x8 afrag[16];

    #define STAGEB(buf, t) do { \
        const u16* s0_ = Btg + (size_t)(t)*4096; \
        GLDS16(s0_ + tid*8,        smem + (buf)*4096 + wave*512); \
        GLDS16(s0_ + 2048 + tid*8, smem + (buf)*4096 + 2048 + wave*512); \
    } while(0)

    STAGEB(0, 0);   // prologue: k-step 0 in flight; agg(0) covers its latency

    for (int r = 0; r < 3; ++r){
        // ---- aggregate relation r into registers ----
        const int* rp = rowp_all + (size_t)r*(NNODES+1);
        int beg = 0, end = 0;
        if (nd < M){ beg = rp[nd]; end = rp[nd+1]; }
        const int coff = (r == 0) ? 0 : ((r == 1) ? e0 : e01);
        const uint4* rc = rec_all + coff;
        float ac[4][4][8] = {};
        float us0 = 0.f, us1 = 0.f, us2 = 0.f, us3 = 0.f;
        uint4 ra = {0,0,0,0};
        uint4 p0 = {0,0,0,0}, p1 = {0,0,0,0}, p2 = {0,0,0,0}, p3 = {0,0,0,0};
        if (beg < end){
            ra = rc[beg];
            const u16* xr = Xg + (size_t)ra.x*128 + quad*8;
            p0 = *(const uint4*)(xr);      p1 = *(const uint4*)(xr + 32);
            p2 = *(const uint4*)(xr + 64); p3 = *(const uint4*)(xr + 96);
        }
        for (int j = beg; j < end; ++j){
            uint4 rb = ra, q0 = p0, q1 = p1, q2 = p2, q3 = p3;
            if (j + 1 < end){
                rb = rc[j+1];
                const u16* xr = Xg + (size_t)rb.x*128 + quad*8;
                q0 = *(const uint4*)(xr);      q1 = *(const uint4*)(xr + 32);
                q2 = *(const uint4*)(xr + 64); q3 = *(const uint4*)(xr + 96);
            }
            float w0 = lo2f(ra.y), w1 = hi2f(ra.y), w2 = lo2f(ra.z), w3 = hi2f(ra.z);
            us0 += w0; us1 += w1; us2 += w2; us3 += w3;
            #define PROCM(m, pv) do { \
                float xv[8]; \
                xv[0]=lo2f(pv.x); xv[1]=hi2f(pv.x); xv[2]=lo2f(pv.y); xv[3]=hi2f(pv.y); \
                xv[4]=lo2f(pv.z); xv[5]=hi2f(pv.z); xv[6]=lo2f(pv.w); xv[7]=hi2f(pv.w); \
                _Pragma("unroll") \
                for (int c = 0; c < 8; ++c){ \
                    ac[0][m][c] = fmaf(w0, xv[c], ac[0][m][c]); \
                    ac[1][m][c] = fmaf(w1, xv[c], ac[1][m][c]); \
                    ac[2][m][c] = fmaf(w2, xv[c], ac[2][m][c]); \
                    ac[3][m][c] = fmaf(w3, xv[c], ac[3][m][c]); \
                } \
            } while(0)
            PROCM(0, p0); PROCM(1, p1); PROCM(2, p2); PROCM(3, p3);
            #undef PROCM
            ra = rb; p0 = q0; p1 = q1; p2 = q2; p3 = q3;
        }
        float ivs[4];
        ivs[0] = us0 > 0.f ? 1.f/us0 : 0.f;
        ivs[1] = us1 > 0.f ? 1.f/us1 : 0.f;
        ivs[2] = us2 > 0.f ? 1.f/us2 : 0.f;
        ivs[3] = us3 > 0.f ? 1.f/us3 : 0.f;
        #pragma unroll
        for (int h = 0; h < 4; ++h){
            #pragma unroll
            for (int m = 0; m < 4; ++m){
                union { bf16x8 v; u32 w[4]; } u;
                u.w[0] = packbf(ac[h][m][0]*ivs[h], ac[h][m][1]*ivs[h]);
                u.w[1] = packbf(ac[h][m][2]*ivs[h], ac[h][m][3]*ivs[h]);
                u.w[2] = packbf(ac[h][m][4]*ivs[h], ac[h][m][5]*ivs[h]);
                u.w[3] = packbf(ac[h][m][6]*ivs[h], ac[h][m][7]*ivs[h]);
                afrag[h*4 + m] = u.v;
            }
        }
        if (r == 0) __syncthreads();   // prologue stage(0) landed (uniform)
        // ---- 16 MFMA k-steps for this rel ----
        #pragma unroll
        for (int m2 = 0; m2 < 16; ++m2){
            STAGEB((m2+1)&1, r*16 + m2 + 1);        // t+1 <= 48, always valid
            const u16* Bs = smem + (m2&1)*4096 + quad*1024;
            #pragma unroll
            for (int j = 0; j < 8; ++j){
                bf16x8 b = *(const bf16x8*)&Bs[(j*16 + r16)*8];
                cacc[j] = __builtin_amdgcn_mfma_f32_16x16x32_bf16(afrag[m2], b, cacc[j], 0,0,0);
            }
            __syncthreads();
        }
    }
    // ---- x-part: 4 k-steps (k 1536..1663), A read directly from Xg ----
    {
        int xrow = nd < M ? nd : M - 1;
        const u16* xr = Xg + (size_t)xrow*128 + quad*8;
        bf16x8 xf0 = *(const bf16x8*)(xr);
        bf16x8 xf1 = *(const bf16x8*)(xr + 32);
        bf16x8 xf2 = *(const bf16x8*)(xr + 64);
        bf16x8 xf3 = *(const bf16x8*)(xr + 96);
        #pragma unroll
        for (int m2 = 0; m2 < 4; ++m2){
            if (m2 < 3) STAGEB((m2+1)&1, 49 + m2);
            const u16* Bs = smem + (m2&1)*4096 + quad*1024;
            bf16x8 a = m2 == 0 ? xf0 : (m2 == 1 ? xf1 : (m2 == 2 ? xf2 : xf3));
            #pragma unroll
            for (int j = 0; j < 8; ++j){
                bf16x8 b = *(const bf16x8*)&Bs[(j*16 + r16)*8];
                cacc[j] = __builtin_amdgcn_mfma_f32_16x16x32_bf16(a, b, cacc[j], 0,0,0);
            }
            __syncthreads();
        }
    }
    #undef STAGEB
    // ---- epilogue ----
    #pragma unroll
    for (int j = 0; j < 8; ++j){
        int col = j*16 + r16;
        float bi = bias[col];
        #pragma unroll
        for (int p = 0; p < 4; ++p){
            int row = row0 + wave*16 + quad*4 + p;
            if (row < M){
                float v = cacc[j][p] + bi;
                if (EPI == 1) Cf[(size_t)row*128 + col] = v;
                else          Cb[(size_t)row*128 + col] = f2b(v);
            }
        }
    }
}

// ---- bf16 MFMA GEMM (used for the fc layer only now), 64x128 tile, BK=64 ----
template<int EPI, int ELR>
__global__ __launch_bounds__(256) void gemm_f(
    const u16* __restrict__ A, int Astride, int K,
    const u16* __restrict__ Bt,
    float* __restrict__ Cf, u16* __restrict__ Cb, int Cstride, int M,
    const float* __restrict__ bias, const float* __restrict__ gamma,
    const float* __restrict__ beta, const float* __restrict__ mean,
    const float* __restrict__ var,
    const u16* __restrict__ wl, float* __restrict__ el)
{
    __shared__ u16 smem[24576];      // 2 x (As 4096 + Bs 8192) u16 = 48KB
    const int tid = threadIdx.x;
    const int row0 = blockIdx.x*64;
    const int lane = tid & 63, wave = tid >> 6;
    const int wm = (wave >> 1)*32, wn = (wave & 1)*64;
    const int r16 = lane & 15, quad = lane >> 4;
    const int swzbase = r16 & 7;
    f32x4 acc[2][4] = {};

    const int r8 = lane >> 3, jc = lane & 7;
    const int soff = ((jc ^ r8) << 3);
    int gA0 = row0 + wave*16 + r8;      if (gA0 >= M) gA0 = M - 1;
    int gA1 = row0 + wave*16 + 8 + r8;  if (gA1 >= M) gA1 = M - 1;
    const u16* srcA0 = A + (size_t)gA0*Astride + soff;
    const u16* srcA1 = A + (size_t)gA1*Astride + soff;
    const u16* srcB0 = Bt + (size_t)(wave*32      + r8)*K + soff;
    const u16* srcB1 = Bt + (size_t)(wave*32 + 8  + r8)*K + soff;
    const u16* srcB2 = Bt + (size_t)(wave*32 + 16 + r8)*K + soff;
    const u16* srcB3 = Bt + (size_t)(wave*32 + 24 + r8)*K + soff;
    const int nk = K >> 6;

    #define STAGE(buf, k0) do { \
        u16* As_ = smem + (buf)*12288; \
        u16* Bs_ = As_ + 4096; \
        GLDS16(srcA0 + (k0), As_ + wave*1024); \
        GLDS16(srcA1 + (k0), As_ + wave*1024 + 512); \
        GLDS16(srcB0 + (k0), Bs_ + wave*2048); \
        GLDS16(srcB1 + (k0), Bs_ + wave*2048 + 512); \
        GLDS16(srcB2 + (k0), Bs_ + wave*2048 + 1024); \
        GLDS16(srcB3 + (k0), Bs_ + wave*2048 + 1536); \
    } while (0)

    STAGE(0, 0);
    __syncthreads();
    for (int t = 0; t < nk; ++t){
        int cur = t & 1;
        if (t + 1 < nk) STAGE(cur ^ 1, (t + 1) << 6);
        const u16* As = smem + cur*12288;
        const u16* Bs = As + 4096;
        #pragma unroll
        for (int ks = 0; ks < 2; ++ks){
            int swz = ((ks*4 + quad) ^ swzbase) << 3;
            bf16x8 a0 = *(const bf16x8*)&As[(wm + r16)*64 + swz];
            bf16x8 a1 = *(const bf16x8*)&As[(wm + 16 + r16)*64 + swz];
            #pragma unroll
            for (int j = 0; j < 4; ++j){
                bf16x8 b = *(const bf16x8*)&Bs[(wn + j*16 + r16)*64 + swz];
                acc[0][j] = __builtin_amdgcn_mfma_f32_16x16x32_bf16(a0, b, acc[0][j], 0,0,0);
                acc[1][j] = __builtin_amdgcn_mfma_f32_16x16x32_bf16(a1, b, acc[1][j], 0,0,0);
            }
        }
        __syncthreads();
    }
    #undef STAGE

    u16* Cs = smem;                  // [64][136] pad (epilogue reuse)
    u16* Ws = smem + 64*136;         // [32][136]
    if (ELR){
        #pragma unroll
        for (int p = 0; p < 2; ++p){
            int idx = tid + p*256;
            int c = idx >> 4, kc = (idx & 15)*8;
            float4 v = make_float4(0.f,0.f,0.f,0.f);
            if (c < 24) v = *(const float4*)(wl + c*128 + kc);
            *(float4*)&Ws[c*136 + kc] = v;
        }
    }
    #pragma unroll
    for (int i = 0; i < 2; ++i){
        #pragma unroll
        for (int p = 0; p < 4; ++p){
            int rl = wm + i*16 + quad*4 + p;
            int row = row0 + rl;
            #pragma unroll
            for (int j = 0; j < 4; ++j){
                int col = wn + j*16 + r16;
                float v = acc[i][j][p] + bias[col];
                if (EPI == 2){
                    float t = fmaxf(v, 0.f);
                    v = (t - mean[col]) * rsqrtf(var[col] + 1e-5f) * gamma[col] + beta[col];
                }
                u16 vb = f2b(v);
                if (row < M){
                    if (EPI == 1) Cf[(size_t)row*Cstride + col] = v;
                    else          Cb[(size_t)row*Cstride + col] = vb;
                }
                if (ELR) Cs[rl*136 + col] = vb;
            }
        }
    }
    if (ELR){
        __syncthreads();
        f32x4 e0 = {}, e1 = {};
        #pragma unroll
        for (int ks = 0; ks < 4; ++ks){
            int ko = ks*32 + quad*8;
            bf16x8 a  = *(const bf16x8*)&Cs[(wave*16 + r16)*136 + ko];
            bf16x8 b0 = *(const bf16x8*)&Ws[r16*136 + ko];
            bf16x8 b1 = *(const bf16x8*)&Ws[(16 + r16)*136 + ko];
            e0 = __builtin_amdgcn_mfma_f32_16x16x32_bf16(a, b0, e0, 0,0,0);
            e1 = __builtin_amdgcn_mfma_f32_16x16x32_bf16(a, b1, e1, 0,0,0);
        }
        #pragma unroll
        for (int p = 0; p < 4; ++p){
            int row = row0 + wave*16 + quad*4 + p;
            if (row < M){
                el[(size_t)row*32 + r16] = e0[p];
                if (r16 < 8) el[(size_t)row*32 + 16 + r16] = e1[p];
            }
        }
    }
}

static inline char* align256(char* p){ return (char*)(((uintptr_t)p + 255) & ~(uintptr_t)255); }

extern "C" void kernel_launch(void* const* d_in, const int* in_sizes, int n_in,
                              void* d_out, int out_size, void* d_ws, size_t ws_size,
                              hipStream_t stream)
{
    const float* x      = (const float*)d_in[0];
    const int* srcs[3]  = {(const int*)d_in[1], (const int*)d_in[3], (const int*)d_in[5]};
    const int* dsts[3]  = {(const int*)d_in[2], (const int*)d_in[4], (const int*)d_in[6]};
    const int  E[3]     = {in_sizes[1], in_sizes[3], in_sizes[5]};
    const float* W0     = (const float*)d_in[7];
    const float* al0    = (const float*)d_in[8];
    const float* ar0    = (const float*)d_in[9];
    const float* resW0  = (const float*)d_in[10];
    const float* b0     = (const float*)d_in[11];
    const float* W1     = (const float*)d_in[12];
    const float* al1    = (const float*)d_in[13];
    const float* ar1    = (const float*)d_in[14];
    const float* resW1  = (const float*)d_in[15];
    const float* b1     = (const float*)d_in[16];
    const float* fcW    = (const float*)d_in[17];
    const float* fcb    = (const float*)d_in[18];
    const float* gamma  = (const float*)d_in[19];
    const float* beta   = (const float*)d_in[20];
    const float* bmean  = (const float*)d_in[21];
    const float* bvar   = (const float*)d_in[22];
    float* out = (float*)d_out;

    // workspace carve
    char* p = (char*)d_ws;
    u16*   Xg    = (u16*)p;   p += (size_t)NNODES*128*2;   p = align256(p);
    u16*   hx1   = (u16*)p;   p += (size_t)NNODES*128*2;   p = align256(p);
    u16*   hmb   = (u16*)p;   p += (size_t)NNODES*128*2;   p = align256(p);
    float* el    = (float*)p; p += (size_t)NNODES*32*4;    p = align256(p);
    int*   cnt   = (int*)p;   p += (size_t)3*NNODES*4;     p = align256(p);
    int*   rowp  = (int*)p;   p += (size_t)3*(NNODES+1)*4; p = align256(p);
    int*   cur   = (int*)p;   p += (size_t)3*NNODES*4;     p = align256(p);
    int*   colb  = (int*)p;   p += (size_t)(E[0]+E[1]+E[2])*4; p = align256(p);
    int*   dste  = (int*)p;   p += (size_t)(E[0]+E[1]+E[2])*4; p = align256(p);
    uint4* rec   = (uint4*)p; p += (size_t)(E[0]+E[1]+E[2])*16; p = align256(p);
    u16*   Btb   = (u16*)p;   p += (size_t)2*128*AW*2;     p = align256(p);
    u16*   wlb   = (u16*)p;   p += (size_t)2*128*128*2;    p = align256(p);
    u16*   fcWtb = (u16*)p;   p += (size_t)128*128*2;      p = align256(p);
    float* biasf = (float*)p; p += (size_t)2*128*4;        p = align256(p);
    int*   parts = (int*)p;   p += (size_t)3*64*4;

    const int NBLK = (NNODES + SCHUNK - 1)/SCHUNK;
    const int MB = (NNODES + 63)/64;
    const int ETOT = E[0] + E[1] + E[2];
    dim3 blk(256);

    hipMemsetAsync(cnt, 0, (size_t)3*NNODES*sizeof(int), stream);
    prep_b <<<(2*128*AW + 255)/256, blk, 0, stream>>>(W0, W1, resW0, resW1, b0, b1, Btb, biasf);
    prep_wl<<<(2*128*128 + 255)/256, blk, 0, stream>>>(W0, W1, al0, ar0, al1, ar1, fcW, wlb, fcWtb);
    xprep_kernel<<<MB, blk, 0, stream>>>(x, Xg, wlb, el, NNODES);
    hist_all<<<(ETOT + 255)/256, blk, 0, stream>>>(dsts[0], dsts[1], dsts[2], E[0], E[1], E[2], cnt);
    scan_part <<<dim3(NBLK,3), blk, 0, stream>>>(cnt, parts, NNODES, NBLK);
    scan_write<<<dim3(NBLK,3), blk, 0, stream>>>(cnt, parts, rowp, cur, NNODES, NBLK);
    scatter_all<<<(ETOT + 255)/256, blk, 0, stream>>>(srcs[0], srcs[1], srcs[2],
                                                      dsts[0], dsts[1], dsts[2],
                                                      E[0], E[1], E[2], cur, colb, dste);

    // ---- layer 0 ----
    wprep<<<(ETOT + 255)/256, blk, 0, stream>>>(colb, dste, E[0], E[0]+E[1], ETOT, el, rec);
    fused_gat<4><<<MB, blk, 0, stream>>>(rowp, rec, E[0], E[0]+E[1], Xg, Btb,
                                         nullptr, hmb, NNODES, biasf);
    gemm_f<2,1><<<MB, blk, 0, stream>>>(hmb, 128, 128, fcWtb, nullptr, hx1, 128, NNODES,
                                        fcb, gamma, beta, bmean, bvar, wlb + 16384, el);

    // ---- layer 1 ----
    wprep<<<(ETOT + 255)/256, blk, 0, stream>>>(colb, dste, E[0], E[0]+E[1], ETOT, el, rec);
    fused_gat<1><<<MB, blk, 0, stream>>>(rowp, rec, E[0], E[0]+E[1], hx1, Btb + (size_t)128*AW,
                                         out, nullptr, NNODES, biasf + 128);
}